// Round 4
// baseline (310.271 us; speedup 1.0000x reference)
//
#include <hip/hip_runtime.h>

// Morphological dilation2d, MI355X (gfx950), fp32.
// out[b,o,h,w] = max_{c,i,j} ( x_zpad[b,c,h+i-2,w+j-2] + w[o,c,i,j] )
// B=4, C=4, O=4, H=W=1024, K=5, PAD=2.
//
// R4: VALU floor ~122 instr/elem = 50 v_pk_add_f32 + ~60 v_max3/v_max + overhead.
//  - thread: 4 px (tx*4) x 8 rows (ty*8) x 2 output channels = 64 elems, 64 acc VGPRs
//  - LDS reads: dense tx*4 b128 pattern (32 lanes cover 128 contiguous dwords ->
//    bank-balanced); 12 row-reads serve 8 output rows (register row-reuse)
//  - weights: pre-duplicated {w,w} pairs in d_ws, loaded via addrspace(4) ->
//    s_load_dwordx2 SGPR pairs consumed directly by v_pk_add_f32 (no VALU cost)
//  - fully unrolled rr x i -> compile-time (d,i) sets, no branches, s_loads hoisted

constexpr int Himg = 1024, Wimg = 1024, Cin = 4, Cout = 4, Kn = 5;
constexpr int TW = 128, THt = 64;  // block tile (x2 output channels)
constexpr int SR = 68;             // staged rows (64 + 4 halo)
constexpr int SC4 = 34;            // 136 staged cols / 4
constexpr int S = 136;             // LDS row stride (floats)
constexpr int NCHUNK = SR * SC4;   // 2312 float4 chunks per channel

typedef float v2f __attribute__((ext_vector_type(2)));
typedef const v2f __attribute__((address_space(4))) cv2f;

// wt2[2*idx] = wt2[2*idx+1] = w[idx]   (idx = ((o*Cin+c)*Kn+i)*Kn+j, row-major)
__global__ void reorg_w(const float* __restrict__ w, float* __restrict__ wt2) {
  int idx = threadIdx.x;
  if (idx < Cout * Cin * Kn * Kn) {
    float v = w[idx];
    wt2[2 * idx + 0] = v;
    wt2[2 * idx + 1] = v;
  }
}

template <bool FAST>
__global__ __launch_bounds__(256, 4) void morph(const float* __restrict__ x,
                                                const float* __restrict__ wt2,
                                                const float* __restrict__ wraw,
                                                float* __restrict__ out) {
  __shared__ __align__(16) float xs[SR * S];  // 36992 B -> 4 blocks/CU
  const int tid = threadIdx.x;
  const int bw = blockIdx.x * TW;
  const int br = blockIdx.y * THt;
  const int b  = blockIdx.z >> 1;
  const int o0 = (blockIdx.z & 1) * 2;
  const int tx = tid & 31;  // 32 col-groups x 4 px
  const int ty = tid >> 5;  // 8 row-groups x 8 rows

  const bool interior = (blockIdx.x > 0) && (blockIdx.x < gridDim.x - 1) &&
                        (blockIdx.y > 0) && (blockIdx.y < gridDim.y - 1);

  float acc[2][8][4];
#pragma unroll
  for (int oo = 0; oo < 2; ++oo)
#pragma unroll
    for (int d = 0; d < 8; ++d)
#pragma unroll
      for (int q = 0; q < 4; ++q) acc[oo][d][q] = -3.4e38f;

#pragma unroll 1
  for (int c = 0; c < Cin; ++c) {
    if (c) __syncthreads();
    // ---- stage channel c: rows br-2..br+65, cols bw-4..bw+131 (zero pad) ----
    const float* src0 = x + (size_t)(b * Cin + c) * Himg * Wimg;
    for (int idx = tid; idx < NCHUNK; idx += 256) {
      const int row = idx / SC4;
      const int ch  = idx - row * SC4;
      const int gr  = br - 2 + row;
      const int gc  = bw - 4 + ch * 4;
      float4 v;
      if (interior) {
        v = *(const float4*)(src0 + (size_t)gr * Wimg + gc);
      } else {
        v = make_float4(0.f, 0.f, 0.f, 0.f);
        if ((unsigned)gr < (unsigned)Himg) {
          const float* src = src0 + (size_t)gr * Wimg;
          if (gc >= 0 && gc <= Wimg - 4) {
            v = *(const float4*)(src + gc);
          } else {
            if ((unsigned)(gc + 0) < (unsigned)Wimg) v.x = src[gc + 0];
            if ((unsigned)(gc + 1) < (unsigned)Wimg) v.y = src[gc + 1];
            if ((unsigned)(gc + 2) < (unsigned)Wimg) v.z = src[gc + 2];
            if ((unsigned)(gc + 3) < (unsigned)Wimg) v.w = src[gc + 3];
          }
        }
      }
      *(float4*)&xs[row * S + ch * 4] = v;
    }
    __syncthreads();

    // ---- compute: oo-outer so only 25 SGPR weight pairs live at a time ----
#pragma unroll
    for (int oo = 0; oo < 2; ++oo) {
      const int wb = ((o0 + oo) * Cin + c) * (Kn * Kn);  // pair-table base
      cv2f* W = (cv2f*)wt2 + wb;                         // s_load_dwordx2 source
      const float* wr = wraw + wb;

#pragma unroll
      for (int rr = 0; rr < 12; ++rr) {
        const float* rb = &xs[(ty * 8 + rr) * S + tx * 4];
        const float4 q0 = *(const float4*)(rb + 0);
        const float4 q1 = *(const float4*)(rb + 4);
        const float4 q2 = *(const float4*)(rb + 8);
        // P[s] = {L[s+2], L[s+3]} for s=0..6 ; even s free sub-pairs, odd = 2 movs
        v2f P[7];
        P[0] = (v2f){q0.z, q0.w};
        P[1] = (v2f){q0.w, q1.x};
        P[2] = (v2f){q1.x, q1.y};
        P[3] = (v2f){q1.y, q1.z};
        P[4] = (v2f){q1.z, q1.w};
        P[5] = (v2f){q1.w, q2.x};
        P[6] = (v2f){q2.x, q2.y};

#pragma unroll
        for (int i = 0; i < Kn; ++i) {
          const int d = rr - i;  // compile-time after unroll
          if (d >= 0 && d < 8) {
            v2f w0, w1, w2, w3, w4;
            if (FAST) {
              w0 = W[i * Kn + 0];
              w1 = W[i * Kn + 1];
              w2 = W[i * Kn + 2];
              w3 = W[i * Kn + 3];
              w4 = W[i * Kn + 4];
            } else {
              float s0 = wr[i * Kn + 0], s1 = wr[i * Kn + 1], s2 = wr[i * Kn + 2];
              float s3 = wr[i * Kn + 3], s4 = wr[i * Kn + 4];
              w0 = (v2f){s0, s0}; w1 = (v2f){s1, s1}; w2 = (v2f){s2, s2};
              w3 = (v2f){s3, s3}; w4 = (v2f){s4, s4};
            }
#pragma unroll
            for (int m = 0; m < 2; ++m) {
              v2f v0 = P[2 * m + 0] + w0;   // v_pk_add_f32, sgpr-pair operand
              v2f v1 = P[2 * m + 1] + w1;
              v2f v2_ = P[2 * m + 2] + w2;
              v2f v3 = P[2 * m + 3] + w3;
              v2f v4 = P[2 * m + 4] + w4;
              float a0 = acc[oo][d][2 * m + 0];
              float a1 = acc[oo][d][2 * m + 1];
              a0 = fmaxf(fmaxf(a0, v0.x), v1.x);  // v_max3_f32
              a0 = fmaxf(fmaxf(a0, v2_.x), v3.x); // v_max3_f32
              a0 = fmaxf(a0, v4.x);
              a1 = fmaxf(fmaxf(a1, v0.y), v1.y);
              a1 = fmaxf(fmaxf(a1, v2_.y), v3.y);
              a1 = fmaxf(a1, v4.y);
              acc[oo][d][2 * m + 0] = a0;
              acc[oo][d][2 * m + 1] = a1;
            }
          }
        }
      }
    }
  }

  // ---- epilogue: 16 coalesced float4 stores ----
#pragma unroll
  for (int oo = 0; oo < 2; ++oo) {
#pragma unroll
    for (int d = 0; d < 8; ++d) {
      const int h = br + ty * 8 + d;
      float4 res = make_float4(acc[oo][d][0], acc[oo][d][1],
                               acc[oo][d][2], acc[oo][d][3]);
      *(float4*)&out[((size_t)(b * Cout + o0 + oo) * Himg + h) * Wimg + bw + tx * 4] = res;
    }
  }
}

extern "C" void kernel_launch(void* const* d_in, const int* in_sizes, int n_in,
                              void* d_out, int out_size, void* d_ws, size_t ws_size,
                              hipStream_t stream) {
  const float* x = (const float*)d_in[0];
  const float* w = (const float*)d_in[1];
  float* out = (float*)d_out;

  dim3 grid(Wimg / TW, Himg / THt, 4 * 2);  // (8, 16, 8) = 1024 blocks = 4/CU

  if (ws_size >= sizeof(float) * 2 * Cout * Cin * Kn * Kn) {
    float* wt2 = (float*)d_ws;
    reorg_w<<<dim3(1), dim3(512), 0, stream>>>(w, wt2);
    morph<true><<<grid, dim3(256), 0, stream>>>(x, wt2, w, out);
  } else {
    morph<false><<<grid, dim3(256), 0, stream>>>(x, nullptr, w, out);
  }
}

// Round 5
// 176.479 us; speedup vs baseline: 1.7581x; 1.7581x over previous
//
#include <hip/hip_runtime.h>

// Morphological dilation2d, MI355X (gfx950), fp32.
// out[b,o,h,w] = max_{c,i,j} ( x_zpad[b,c,h+i-2,w+j-2] + w[o,c,i,j] )
// B=4, C=4, O=4, H=W=1024, K=5, PAD=2.
//
// R5: floor = 100 VALU slots/output (50 pk_add halves + 50 max3). Anti-spill
// structure (R4 lesson: acc indexing must be static; no giant unroll bodies).
//  - thread: 8 px x 2 output rows x ALL 4 oc = 64 outputs, acc[2][4][8] static
//  - rolling rowset A/B (SSA rotation in 5-iter unrolled i-loop) -> 6 LDS
//    row-reads per channel (optimal), 4 x ds_read_b128 each
//  - even pk pairs = quad subregisters (free); 5 odd pairs prebuilt per row
//    (10 movs, amortized over 4 oc x 2 d)
//  - weights: {w,w} pairs in d_ws via addrspace(4) -> s_load_dwordx2, consumed
//    as the 64-bit SGPR operand of v_pk_add_f32 (zero VALU, zero VGPR)

constexpr int Himg = 1024, Wimg = 1024, Cin = 4, Cout = 4, Kn = 5;
constexpr int TW = 128, THt = 32;  // block tile: 128W x 32H x 4oc
constexpr int SR = THt + 4;        // 36 staged rows
constexpr int SC4 = 34;            // 136 staged cols / 4  (bw-4 .. bw+131)
constexpr int S = 136;             // LDS row stride, mult of 4 (16B rows)
constexpr int NCHUNK = SR * SC4;   // 1224 float4 chunks per channel

typedef float v2f __attribute__((ext_vector_type(2)));
typedef const v2f __attribute__((address_space(4))) cv2f;

// src idx = ((o*Cin+c)*Kn+i)*Kn+j  ->  dst pair ((c*Kn+i)*Cout+o)*Kn+j = {w,w}
__global__ void reorg_w(const float* __restrict__ w, float* __restrict__ wt2) {
  int idx = threadIdx.x;
  if (idx < Cout * Cin * Kn * Kn) {
    int o  = idx / (Cin * Kn * Kn);
    int r  = idx % (Cin * Kn * Kn);
    int c  = r / (Kn * Kn);
    int r2 = r % (Kn * Kn);
    int i  = r2 / Kn, j = r2 % Kn;
    int dst = (((c * Kn + i) * Cout + o) * Kn + j) * 2;
    wt2[dst + 0] = w[idx];
    wt2[dst + 1] = w[idx];
  }
}

// One staged input row's window for this thread: L[t] = staged[row][tx*8 + t],
// t = p + j + 2 for px p in 0..7, j in 0..4  ->  t in [2,12].
struct Row {
  float4 q0, q1, q2, q3;      // L[0..15], even-aligned register quads
  v2f o3, o5, o7, o9, o11;    // odd pairs {L[s],L[s+1]}, s = 3,5,7,9,11
};

__device__ __forceinline__ Row read_row(const float* rb) {
  Row R;
  R.q0 = *(const float4*)(rb + 0);
  R.q1 = *(const float4*)(rb + 4);
  R.q2 = *(const float4*)(rb + 8);
  R.q3 = *(const float4*)(rb + 12);
  R.o3  = (v2f){R.q0.w, R.q1.x};
  R.o5  = (v2f){R.q1.y, R.q1.z};
  R.o7  = (v2f){R.q1.w, R.q2.x};
  R.o9  = (v2f){R.q2.y, R.q2.z};
  R.o11 = (v2f){R.q2.w, R.q3.x};
  return R;
}

// acc[8] += max-plus of row R with weight pairs w0..w4 (pk_add + max3 trees).
__device__ __forceinline__ void accum(const Row& R, v2f w0, v2f w1, v2f w2,
                                      v2f w3, v2f w4, float (&a)[8]) {
  const v2f E2  = (v2f){R.q0.z, R.q0.w};
  const v2f E4  = (v2f){R.q1.x, R.q1.y};
  const v2f E6  = (v2f){R.q1.z, R.q1.w};
  const v2f E8  = (v2f){R.q2.x, R.q2.y};
  const v2f E10 = (v2f){R.q2.z, R.q2.w};
  const v2f E12 = (v2f){R.q3.x, R.q3.y};
#define MPAIR(m, P0, P1, P2, P3, P4)                                   \
  do {                                                                 \
    v2f r0 = P0 + w0, r1 = P1 + w1, r2 = P2 + w2;                      \
    v2f r3 = P3 + w3, r4 = P4 + w4;                                    \
    float t0 = fmaxf(fmaxf(a[2 * m + 0], r0.x), r1.x);                 \
    float u0 = fmaxf(fmaxf(r2.x, r3.x), r4.x);                         \
    a[2 * m + 0] = fmaxf(t0, u0);                                      \
    float t1 = fmaxf(fmaxf(a[2 * m + 1], r0.y), r1.y);                 \
    float u1 = fmaxf(fmaxf(r2.y, r3.y), r4.y);                         \
    a[2 * m + 1] = fmaxf(t1, u1);                                      \
  } while (0)
  MPAIR(0, E2, R.o3, E4, R.o5, E6);
  MPAIR(1, E4, R.o5, E6, R.o7, E8);
  MPAIR(2, E6, R.o7, E8, R.o9, E10);
  MPAIR(3, E8, R.o9, E10, R.o11, E12);
#undef MPAIR
}

template <bool FAST>
__global__ __launch_bounds__(256) void morph(const float* __restrict__ x,
                                             const float* __restrict__ wt2,
                                             const float* __restrict__ wraw,
                                             float* __restrict__ out) {
  __shared__ __align__(16) float xs[SR * S];  // 19584 B
  const int tid = threadIdx.x;
  const int bw = blockIdx.x * TW;
  const int br = blockIdx.y * THt;
  const int b  = blockIdx.z;
  const int tx = tid & 15;  // 16 col-groups x 8 px
  const int ty = tid >> 4;  // 16 row-groups x 2 rows

  const bool interior = (blockIdx.x > 0) && (blockIdx.x < gridDim.x - 1) &&
                        (blockIdx.y > 0) && (blockIdx.y < gridDim.y - 1);

  cv2f* cw = (cv2f*)wt2;

  float acc[2][4][8];
#pragma unroll
  for (int d = 0; d < 2; ++d)
#pragma unroll
    for (int oc = 0; oc < Cout; ++oc)
#pragma unroll
      for (int p = 0; p < 8; ++p) acc[d][oc][p] = -3.4e38f;

#pragma unroll 1
  for (int c = 0; c < Cin; ++c) {
    if (c) __syncthreads();
    // ---- stage channel c: rows br-2..br+33, cols bw-4..bw+131, zero pad ----
    const float* src0 = x + (size_t)(b * Cin + c) * Himg * Wimg;
#pragma unroll
    for (int k = 0; k < 5; ++k) {
      const int idx = tid + k * 256;
      if (idx < NCHUNK) {
        const int row = idx / SC4;
        const int ch  = idx - row * SC4;
        const int gr  = br - 2 + row;
        const int gc  = bw - 4 + ch * 4;
        float4 v;
        if (interior) {
          v = *(const float4*)(src0 + (size_t)gr * Wimg + gc);
        } else {
          v = make_float4(0.f, 0.f, 0.f, 0.f);
          if ((unsigned)gr < (unsigned)Himg) {
            const float* src = src0 + (size_t)gr * Wimg;
            if (gc >= 0 && gc <= Wimg - 4) {
              v = *(const float4*)(src + gc);
            } else {
              if ((unsigned)(gc + 0) < (unsigned)Wimg) v.x = src[gc + 0];
              if ((unsigned)(gc + 1) < (unsigned)Wimg) v.y = src[gc + 1];
              if ((unsigned)(gc + 2) < (unsigned)Wimg) v.z = src[gc + 2];
              if ((unsigned)(gc + 3) < (unsigned)Wimg) v.w = src[gc + 3];
            }
          }
        }
        *(float4*)&xs[row * S + ch * 4] = v;
      }
    }
    __syncthreads();

    // ---- compute: rolling rowsets, 6 row-reads per channel ----
    const float* wbase = &xs[(ty * 2) * S + tx * 8];
    Row A = read_row(wbase);          // staged row ty*2   -> d=0 at i
    Row B = read_row(wbase + S);      // staged row ty*2+1 -> d=1 at i

#pragma unroll
    for (int i = 0; i < Kn; ++i) {
#pragma unroll
      for (int oc = 0; oc < Cout; ++oc) {
        v2f w0, w1, w2, w3, w4;
        if (FAST) {
          cv2f* W = cw + ((c * Kn + i) * Cout + oc) * Kn;
          w0 = W[0]; w1 = W[1]; w2 = W[2]; w3 = W[3]; w4 = W[4];
        } else {
          const float* wr = wraw + ((oc * Cin + c) * Kn + i) * Kn;
          float s0 = wr[0], s1 = wr[1], s2 = wr[2], s3 = wr[3], s4 = wr[4];
          w0 = (v2f){s0, s0}; w1 = (v2f){s1, s1}; w2 = (v2f){s2, s2};
          w3 = (v2f){s3, s3}; w4 = (v2f){s4, s4};
        }
        accum(A, w0, w1, w2, w3, w4, acc[0][oc]);
        accum(B, w0, w1, w2, w3, w4, acc[1][oc]);
      }
      if (i < Kn - 1) {
        A = B;                                  // SSA rename after unroll
        B = read_row(wbase + (i + 2) * S);      // staged row ty*2+i+2
      }
    }
  }

  // ---- epilogue: 16 coalesced float4 stores ----
#pragma unroll
  for (int d = 0; d < 2; ++d) {
    const int h = br + ty * 2 + d;
#pragma unroll
    for (int oc = 0; oc < Cout; ++oc) {
      const size_t base = ((size_t)(b * Cout + oc) * Himg + h) * Wimg + bw + tx * 8;
      *(float4*)&out[base + 0] = make_float4(acc[d][oc][0], acc[d][oc][1],
                                             acc[d][oc][2], acc[d][oc][3]);
      *(float4*)&out[base + 4] = make_float4(acc[d][oc][4], acc[d][oc][5],
                                             acc[d][oc][6], acc[d][oc][7]);
    }
  }
}

extern "C" void kernel_launch(void* const* d_in, const int* in_sizes, int n_in,
                              void* d_out, int out_size, void* d_ws, size_t ws_size,
                              hipStream_t stream) {
  const float* x = (const float*)d_in[0];
  const float* w = (const float*)d_in[1];
  float* out = (float*)d_out;

  dim3 grid(Wimg / TW, Himg / THt, 4);  // (8, 32, 4) = 1024 blocks

  if (ws_size >= sizeof(float) * 2 * Cout * Cin * Kn * Kn) {
    float* wt2 = (float*)d_ws;
    reorg_w<<<dim3(1), dim3(512), 0, stream>>>(w, wt2);
    morph<true><<<grid, dim3(256), 0, stream>>>(x, wt2, w, out);
  } else {
    morph<false><<<grid, dim3(256), 0, stream>>>(x, nullptr, w, out);
  }
}